// Round 15
// baseline (305.629 us; speedup 1.0000x reference)
//
#include <hip/hip_runtime.h>

// ---------------------------------------------------------------------------
// TopoTransform: batched sign-fixed QR (MGS) + per-site channel mix.
//   problem 0: B=32, C=64,  S=784   problem 1: B=32, C=256, S=196
//   out[b][c][s] = sum_k Q[s][c][k] * x[b][k][s],  Q[s] = qr(W[s]) sign-fixed
//
// R15: revert R14 (K=8: owner chain 4x + spill returned -> 294us). Base =
// R12 (250us best). Single change: K=4 — retire 4 cols/round via TWO owner
// groups in the SAME wave (2m+2 even: mini_mgs2; 2m+3 odd: 2 dots + mini,
// chained by intra-wave DS program order, validated bit-exact in R14).
// Rounds/panel 64->32, barriers ~130->~68; per-round fixed overhead
// (~1.5-2K cyc, inferred from R13/R14 K-scaling) halves in total while the
// owner scope stays lean (mini+2dots+mini, fence-separated — R9/R14 spill
// lesson). Per-column op order unchanged -> absmax EXACTLY 0.09765625.
// Sentinels: WRITE_SIZE 12,544 KB, VGPR 64.
// ---------------------------------------------------------------------------

static constexpr int BB = 32;  // batch

#define SCHED_FENCE() __builtin_amdgcn_sched_barrier(0)

// -------- DPP 16-lane all-reduce (sum) on the VALU pipe --------------------
template<int CTRL>
__device__ __forceinline__ float dpp_add(float x) {
    int y = __builtin_amdgcn_update_dpp(0, __float_as_int(x), CTRL, 0xF, 0xF, false);
    return x + __int_as_float(y);
}
__device__ __forceinline__ float rowred16(float p) {
    p = dpp_add<0x128>(p);  // row_ror:8
    p = dpp_add<0x124>(p);  // row_ror:4
    p = dpp_add<0x122>(p);  // row_ror:2
    p = dpp_add<0x121>(p);  // row_ror:1
    return p;               // all 16 lanes of the row hold the sum
}

// qpan slot layout (1KB per col j): row r = r16*16 + 4g + e stored at
// float idx j*256 + g*64 + ((r16 ^ 2g) << 2) + e.
__device__ __forceinline__ int qoff(int j, int g, int r16) {
    return j * 256 + g * 64 + ((r16 ^ (2 * g)) << 2);
}

// -------- transpose: in (R, S) row-major -> out (S, R) row-major ----------
__global__ __launch_bounds__(256) void tkern(const float* __restrict__ in,
                                             float* __restrict__ out,
                                             int R, int S) {
    __shared__ float tile[32][33];
    const int tx = threadIdx.x, ty = threadIdx.y;
    const int s0 = blockIdx.x * 32, r0 = blockIdx.y * 32;
    #pragma unroll
    for (int i = ty; i < 32; i += 8) {
        int r = r0 + i, s = s0 + tx;
        tile[i][tx] = (r < R && s < S) ? in[(size_t)r * S + s] : 0.f;
    }
    __syncthreads();
    #pragma unroll
    for (int i = ty; i < 32; i += 8) {
        int s = s0 + i, r = r0 + tx;
        if (s < S && r < R) out[(size_t)s * R + r] = tile[tx][i];
    }
}

// ===========================================================================
// C=64 path (register-resident MGS + chunked apply), takes thread id and an
// LDS slice so 4 sites pack into one 1024-thread block. (R12, unchanged.)
// ===========================================================================
template<int C, int CT, int KC>
__device__ __forceinline__ void qr_body(const float* __restrict__ W,
                                        float* __restrict__ XY,
                                        float* __restrict__ sm, int t) {
    constexpr int RT = 16;
    constexpr int TR = C / RT;
    constexpr int THREADS = RT * CT;
    constexpr int QSTR = TR + 4;
    constexpr int XSTR = C + 4;

    float* qs = sm;                       // 2 * RT*QSTR
    float* xs = sm + 2 * RT * QSTR;       // BB * XSTR
    float* qc = xs + BB * XSTR;           // KC * C

    const int rb = t & 15;
    const int cb = t >> 4;

    float a[TR][4];
    {
        const float* Wp = W + (size_t)(rb * TR) * C + cb * 4;
        #pragma unroll
        for (int i = 0; i < TR; ++i) {
            float4 v = *reinterpret_cast<const float4*>(Wp + (size_t)i * C);
            a[i][0] = v.x; a[i][1] = v.y; a[i][2] = v.z; a[i][3] = v.w;
        }
    }
    {
        #pragma unroll
        for (int v = 0; v < (BB * C) / (4 * THREADS); ++v) {
            int idx = 4 * (t + v * THREADS);
            int b = idx / C, k = idx % C;
            float4 x4 = *reinterpret_cast<const float4*>(XY + idx);
            *reinterpret_cast<float4*>(&xs[b * XSTR + k]) = x4;
        }
    }

    int buf = 0;
    #pragma unroll 1
    for (int j = 0; j < C; ++j) {
        const int cbj = j >> 2, jj = j & 3;
        if (cb == cbj) {
            #pragma unroll
            for (int q = 0; q < 4; ++q) {
                if (q == jj) {
                    float p = 0.f;
                    #pragma unroll
                    for (int i = 0; i < TR; ++i) p += a[i][q] * a[i][q];
                    p = rowred16(p);
                    const float rn = 1.0f / sqrtf(p);
                    #pragma unroll
                    for (int i = 0; i < TR; ++i) a[i][q] *= rn;
                    #pragma unroll
                    for (int i = 0; i < TR; i += 4) {
                        *reinterpret_cast<float4*>(&qs[buf * RT * QSTR + rb * QSTR + i]) =
                            make_float4(a[i][q], a[i+1][q], a[i+2][q], a[i+3][q]);
                    }
                }
            }
        }
        __syncthreads();
        if (cb * 4 + 3 > j) {
            float qv[TR];
            #pragma unroll
            for (int i = 0; i < TR; i += 4) {
                float4 v = *reinterpret_cast<const float4*>(&qs[buf * RT * QSTR + rb * QSTR + i]);
                qv[i] = v.x; qv[i+1] = v.y; qv[i+2] = v.z; qv[i+3] = v.w;
            }
            #pragma unroll
            for (int q = 0; q < 4; ++q) {
                if (cb * 4 + q > j) {
                    float p = 0.f;
                    #pragma unroll
                    for (int i = 0; i < TR; ++i) p += a[i][q] * qv[i];
                    p = rowred16(p);
                    #pragma unroll
                    for (int i = 0; i < TR; ++i) a[i][q] -= p * qv[i];
                }
            }
        }
        buf ^= 1;
    }

    const int u  = t % (C / 4);
    const int bp = t / (C / 4);
    float acc[2][4] = {{0,0,0,0},{0,0,0,0}};

    #pragma unroll 1
    for (int ch = 0; ch < C / KC; ++ch) {
        __syncthreads();
        if (cb >= (ch * KC) / 4 && cb < ((ch + 1) * KC) / 4) {
            #pragma unroll
            for (int q = 0; q < 4; ++q) {
                const int kk = cb * 4 + q - ch * KC;
                const int swz = (kk & 7) << 2;
                #pragma unroll
                for (int i = 0; i < TR; i += 4) {
                    const int cout = rb * TR + i;
                    *reinterpret_cast<float4*>(&qc[kk * C + (cout ^ swz)]) =
                        make_float4(a[i][q], a[i+1][q], a[i+2][q], a[i+3][q]);
                }
            }
        }
        __syncthreads();
        #pragma unroll
        for (int kk = 0; kk < KC; kk += 4) {
            const int k = ch * KC + kk;
            float4 x0 = *reinterpret_cast<const float4*>(&xs[(2*bp    ) * XSTR + k]);
            float4 x1 = *reinterpret_cast<const float4*>(&xs[(2*bp + 1) * XSTR + k]);
            #pragma unroll
            for (int m = 0; m < 4; ++m) {
                const int swz = ((kk + m) & 7) << 2;
                float4 qv4 = *reinterpret_cast<const float4*>(&qc[(kk + m) * C + ((4 * u) ^ swz)]);
                const float xa = (&x0.x)[m], xb = (&x1.x)[m];
                acc[0][0] += xa * qv4.x; acc[0][1] += xa * qv4.y;
                acc[0][2] += xa * qv4.z; acc[0][3] += xa * qv4.w;
                acc[1][0] += xb * qv4.x; acc[1][1] += xb * qv4.y;
                acc[1][2] += xb * qv4.z; acc[1][3] += xb * qv4.w;
            }
        }
    }
    {
        *reinterpret_cast<float4*>(XY + (2*bp    ) * C + 4 * u) =
            make_float4(acc[0][0], acc[0][1], acc[0][2], acc[0][3]);
        *reinterpret_cast<float4*>(XY + (2*bp + 1) * C + 4 * u) =
            make_float4(acc[1][0], acc[1][1], acc[1][2], acc[1][3]);
    }
}

// ===========================================================================
// C=256 left-looking 2-panel MGS (R12 core arithmetic; K=4 rounds).
// ===========================================================================
__device__ __forceinline__ void dot_upd(float (&a)[2][16], const float* qpan,
                                        int j, int rb) {
    const float4 q40 = *reinterpret_cast<const float4*>(&qpan[qoff(j, 0, rb)]);
    const float4 q41 = *reinterpret_cast<const float4*>(&qpan[qoff(j, 1, rb)]);
    const float4 q42 = *reinterpret_cast<const float4*>(&qpan[qoff(j, 2, rb)]);
    const float4 q43 = *reinterpret_cast<const float4*>(&qpan[qoff(j, 3, rb)]);
    float p0 = 0.f, p1 = 0.f;
    p0 += a[0][ 0]*q40.x; p1 += a[1][ 0]*q40.x;
    p0 += a[0][ 1]*q40.y; p1 += a[1][ 1]*q40.y;
    p0 += a[0][ 2]*q40.z; p1 += a[1][ 2]*q40.z;
    p0 += a[0][ 3]*q40.w; p1 += a[1][ 3]*q40.w;
    p0 += a[0][ 4]*q41.x; p1 += a[1][ 4]*q41.x;
    p0 += a[0][ 5]*q41.y; p1 += a[1][ 5]*q41.y;
    p0 += a[0][ 6]*q41.z; p1 += a[1][ 6]*q41.z;
    p0 += a[0][ 7]*q41.w; p1 += a[1][ 7]*q41.w;
    p0 += a[0][ 8]*q42.x; p1 += a[1][ 8]*q42.x;
    p0 += a[0][ 9]*q42.y; p1 += a[1][ 9]*q42.y;
    p0 += a[0][10]*q42.z; p1 += a[1][10]*q42.z;
    p0 += a[0][11]*q42.w; p1 += a[1][11]*q42.w;
    p0 += a[0][12]*q43.x; p1 += a[1][12]*q43.x;
    p0 += a[0][13]*q43.y; p1 += a[1][13]*q43.y;
    p0 += a[0][14]*q43.z; p1 += a[1][14]*q43.z;
    p0 += a[0][15]*q43.w; p1 += a[1][15]*q43.w;
    p0 = rowred16(p0); p1 = rowred16(p1);
    a[0][ 0] -= p0*q40.x; a[0][ 1] -= p0*q40.y;
    a[0][ 2] -= p0*q40.z; a[0][ 3] -= p0*q40.w;
    a[0][ 4] -= p0*q41.x; a[0][ 5] -= p0*q41.y;
    a[0][ 6] -= p0*q41.z; a[0][ 7] -= p0*q41.w;
    a[0][ 8] -= p0*q42.x; a[0][ 9] -= p0*q42.y;
    a[0][10] -= p0*q42.z; a[0][11] -= p0*q42.w;
    a[0][12] -= p0*q43.x; a[0][13] -= p0*q43.y;
    a[0][14] -= p0*q43.z; a[0][15] -= p0*q43.w;
    a[1][ 0] -= p1*q40.x; a[1][ 1] -= p1*q40.y;
    a[1][ 2] -= p1*q40.z; a[1][ 3] -= p1*q40.w;
    a[1][ 4] -= p1*q41.x; a[1][ 5] -= p1*q41.y;
    a[1][ 6] -= p1*q41.z; a[1][ 7] -= p1*q41.w;
    a[1][ 8] -= p1*q42.x; a[1][ 9] -= p1*q42.y;
    a[1][10] -= p1*q42.z; a[1][11] -= p1*q42.w;
    a[1][12] -= p1*q43.x; a[1][13] -= p1*q43.y;
    a[1][14] -= p1*q43.z; a[1][15] -= p1*q43.w;
}

__device__ __forceinline__ void mini_mgs2(float (&a)[2][16], float* qpan,
                                          int jx, int rb) {
    float p = 0.f;
    #pragma unroll
    for (int i = 0; i < 16; ++i) p += a[0][i] * a[0][i];
    p = rowred16(p);
    float rn = 1.0f / sqrtf(p);
    #pragma unroll
    for (int i = 0; i < 16; ++i) a[0][i] *= rn;
    #pragma unroll
    for (int g = 0; g < 4; ++g) {
        *reinterpret_cast<float4*>(&qpan[qoff(jx, g, rb)]) =
            make_float4(a[0][4*g], a[0][4*g+1], a[0][4*g+2], a[0][4*g+3]);
    }
    float q = 0.f;
    #pragma unroll
    for (int i = 0; i < 16; ++i) q += a[1][i] * a[0][i];
    q = rowred16(q);
    #pragma unroll
    for (int i = 0; i < 16; ++i) a[1][i] -= q * a[0][i];
    p = 0.f;
    #pragma unroll
    for (int i = 0; i < 16; ++i) p += a[1][i] * a[1][i];
    p = rowred16(p);
    rn = 1.0f / sqrtf(p);
    #pragma unroll
    for (int i = 0; i < 16; ++i) a[1][i] *= rn;
    #pragma unroll
    for (int g = 0; g < 4; ++g) {
        *reinterpret_cast<float4*>(&qpan[qoff(jx + 1, g, rb)]) =
            make_float4(a[1][4*g], a[1][4*g+1], a[1][4*g+2], a[1][4*g+3]);
    }
}

// fused rank-1 apply for col j (j ascending across calls)
__device__ __forceinline__ void apply1(float (&y0)[4], float (&y1)[4],
                                       const float* qpan, const float* xsb,
                                       int j, int u, int v) {
    float4 q4 = *reinterpret_cast<const float4*>(&qpan[qoff(j, u & 3, u >> 2)]);
    const float xa = xsb[j*33 + 2*v];
    const float xb = xsb[j*33 + 2*v + 1];
    y0[0] += xa*q4.x; y0[1] += xa*q4.y; y0[2] += xa*q4.z; y0[3] += xa*q4.w;
    y1[0] += xb*q4.x; y1[1] += xb*q4.y; y1[2] += xb*q4.z; y1[3] += xb*q4.w;
}

// K=4 rounds: prologue retires cols 0..3 (wave-0 groups 0,1 chained via
// intra-wave DS program order — validated in R14). Round m: apply cols
// 4m..4m+3, dots vs them for cb>2m+1, owner groups 2m+2 (mini) and 2m+3
// (2 dots + mini, intra-wave chained) retire cols 4m+4..4m+7.
__device__ void panel_mgs(float (&a)[2][16], float (&y0)[4], float (&y1)[4],
                          float* qpan, const float* xsb,
                          int rb, int cb, int u, int v) {
    if (cb == 0) mini_mgs2(a, qpan, 0, rb);
    SCHED_FENCE();
    if (cb == 1) {
        dot_upd(a, qpan, 0, rb); SCHED_FENCE();
        dot_upd(a, qpan, 1, rb); SCHED_FENCE();
        mini_mgs2(a, qpan, 2, rb);
    }
    __syncthreads();   // also orders xsb staging / prologue qpan writes
    #pragma unroll 1
    for (int m = 0; m < 32; ++m) {
        // apply first: independent post-barrier work (fills q-read latency)
        apply1(y0, y1, qpan, xsb, 4*m,     u, v);
        apply1(y0, y1, qpan, xsb, 4*m + 1, u, v);
        apply1(y0, y1, qpan, xsb, 4*m + 2, u, v);
        apply1(y0, y1, qpan, xsb, 4*m + 3, u, v);
        SCHED_FENCE();   // cap liveness: apply regs retire before dot phase
        if (cb > 2*m + 1) {
            dot_upd(a, qpan, 4*m,     rb); SCHED_FENCE();
            dot_upd(a, qpan, 4*m + 1, rb); SCHED_FENCE();
            dot_upd(a, qpan, 4*m + 2, rb); SCHED_FENCE();
            dot_upd(a, qpan, 4*m + 3, rb); SCHED_FENCE();
            if (cb == 2*m + 2) mini_mgs2(a, qpan, 4*m + 4, rb);
            SCHED_FENCE();
            if (cb == 2*m + 3) {
                dot_upd(a, qpan, 4*m + 4, rb); SCHED_FENCE();
                dot_upd(a, qpan, 4*m + 5, rb); SCHED_FENCE();
                mini_mgs2(a, qpan, 4*m + 6, rb);
            }
        }
        __syncthreads();
    }
}

__device__ __forceinline__ void qr256_site(const float* __restrict__ Wp,
                                           float* __restrict__ Xp,
                                           float* __restrict__ sm, int t) {
    float* qpan = sm;            // 128 KiB: finished q's, 1KB/col slot
    float* xsb  = sm + 32768;    // 16.5 KiB: X panel [col][b], pad 33

    const int rb = t & 15;
    const int cb = t >> 4;
    const int u  = t & 63;
    const int v  = t >> 6;

    float a[2][16];
    float y0[4] = {0,0,0,0};
    float y1[4] = {0,0,0,0};

    // ---- panel 0: load W cols [0,128) + stage X cols [0,128) ----
    #pragma unroll
    for (int i = 0; i < 16; ++i) {
        float2 w2 = *reinterpret_cast<const float2*>(
            Wp + (size_t)(rb*16 + i) * 256 + 2*cb);
        a[0][i] = w2.x; a[1][i] = w2.y;
    }
    {
        const int tj = t & 127, tb = t >> 7;
        #pragma unroll
        for (int d = 0; d < 4; ++d)
            xsb[tj*33 + 4*tb + d] = Xp[(4*tb + d)*256 + tj];
    }
    panel_mgs(a, y0, y1, qpan, xsb, rb, cb, u, v);

    // ---- glue: reload W cols [128,256), restage X, cross-pass ----
    __syncthreads();   // panel-0 consumers done before xsb is overwritten
    #pragma unroll
    for (int i = 0; i < 16; ++i) {
        float2 w2 = *reinterpret_cast<const float2*>(
            Wp + (size_t)(rb*16 + i) * 256 + 128 + 2*cb);
        a[0][i] = w2.x; a[1][i] = w2.y;
    }
    {
        const int tj = t & 127, tb = t >> 7;
        #pragma unroll
        for (int d = 0; d < 4; ++d)
            xsb[tj*33 + 4*tb + d] = Xp[(4*tb + d)*256 + 128 + tj];
    }
    // cross-pass: orthogonalize both register cols vs Q0 (barrier-free;
    // qpan read-only here, xsb writes touch a disjoint region)
    #pragma unroll 1
    for (int k = 0; k < 128; ++k) {
        dot_upd(a, qpan, k, rb);
        SCHED_FENCE();
    }
    __syncthreads();   // cross-pass done everywhere before qpan overwrite

    // ---- panel 1 ----
    panel_mgs(a, y0, y1, qpan, xsb, rb, cb, u, v);

    // ---- write Y in place over X (coalesced float4) ----
    *reinterpret_cast<float4*>(Xp + (size_t)(2*v    )*256 + 4*u) =
        make_float4(y0[0], y0[1], y0[2], y0[3]);
    *reinterpret_cast<float4*>(Xp + (size_t)(2*v + 1)*256 + 4*u) =
        make_float4(y1[0], y1[1], y1[2], y1[3]);
}

// ===========================================================================
// Mega-kernel: 256 blocks x 1024 thr, LDS 148KB -> 1 block/CU.
//   blocks 0..195: one C=256 site.  blocks 196..255: packed 4x C=64 sites.
// ===========================================================================
static constexpr int SM64 = 2*16*8 + 32*68 + 64*64;   // 6528 floats per site

__global__ __launch_bounds__(1024) void qr_all(const float* __restrict__ W0,
                                               const float* __restrict__ W1,
                                               float* __restrict__ XY0,
                                               float* __restrict__ XY1) {
    __shared__ float sm[32768 + 128*33];   // 36992 floats = 147,968 B
    const int bid = blockIdx.x;
    const int t   = threadIdx.x;
    if (bid < 196) {
        qr256_site(W1 + (size_t)bid * 65536, XY1 + (size_t)bid * 8192, sm, t);
    } else {
        const int sl = t >> 8;     // sub-site 0..3
        const int tt = t & 255;
        float* smL = sm + sl * SM64;
        #pragma unroll 1
        for (int uu = bid - 196; uu < 196; uu += 60) {
            const int site = 4 * uu + sl;
            qr_body<64, 16, 64>(W0 + (size_t)site * 4096,
                                XY0 + (size_t)site * 2048, smL, tt);
            __syncthreads();   // LDS slice safe to reuse next unit
        }
    }
}

extern "C" void kernel_launch(void* const* d_in, const int* in_sizes, int n_in,
                              void* d_out, int out_size, void* d_ws, size_t ws_size,
                              hipStream_t stream) {
    (void)in_sizes; (void)n_in; (void)out_size; (void)ws_size;
    const float* x0 = (const float*)d_in[0];  // (32, 64, 784)
    const float* x1 = (const float*)d_in[1];  // (32, 256, 196)
    const float* W0 = (const float*)d_in[2];  // (784, 64, 64)
    const float* W1 = (const float*)d_in[3];  // (196, 256, 256)
    float* y0  = (float*)d_out;               // (32, 64, 784) flat
    float* y1  = y0 + 1605632;                // (32, 256, 196) flat
    float* xt0 = (float*)d_ws;                // (784, 32*64)
    float* xt1 = xt0 + 1605632;               // (196, 32*256)

    dim3 tb(32, 8);
    // x (B*C, S) -> xt (S, B*C)
    tkern<<<dim3(25,  64), tb, 0, stream>>>(x0, xt0, 2048, 784);
    tkern<<<dim3(7,  256), tb, 0, stream>>>(x1, xt1, 8192, 196);
    // fused QR + apply, both problems in one dispatch (Y overwrites xt)
    qr_all<<<256, 1024, 0, stream>>>(W0, W1, xt0, xt1);
    // xt (S, B*C) -> y (B*C, S)
    tkern<<<dim3(64,  25), tb, 0, stream>>>(xt0, y0, 784, 2048);
    tkern<<<dim3(256,  7), tb, 0, stream>>>(xt1, y1, 196, 8192);
}

// Round 16
// 250.044 us; speedup vs baseline: 1.2223x; 1.2223x over previous
//
#include <hip/hip_runtime.h>

// ---------------------------------------------------------------------------
// TopoTransform: batched sign-fixed QR (MGS) + per-site channel mix.
//   problem 0: B=32, C=64,  S=784   problem 1: B=32, C=256, S=196
//   out[b][c][s] = sum_k Q[s][c][k] * x[b][k][s],  Q[s] = qr(W[s]) sign-fixed
//
// R16 = R12 restored (best verified: 250.1us). R13 (apply-hoist) neutral,
// R14 (K=8) and R15 (K=4) both regressed via owner-chain growth + register
// liveness blowup (WRITE_SIZE 23.5/72.5 MB spill). The K=2 round body is at
// the 64-VGPR liveness edge; per-retirement fixed cost (~1.8K cyc x 256)
// cannot be amortized further without spilling. Remaining levers require
// arithmetic reordering, which risks the 5% absmax margin (0.0977/0.1025).
// Structure: 256-block mega-kernel, LDS 148KB -> 1 block/CU; blocks 0..195
// run one C=256 left-looking 2-panel MGS site (K=2 rounds, fused apply,
// sched fences); blocks 196..255 loop packed 4x C=64 sites, hidden under
// the C=256 work. absmax EXACTLY 0.09765625.
// ---------------------------------------------------------------------------

static constexpr int BB = 32;  // batch

#define SCHED_FENCE() __builtin_amdgcn_sched_barrier(0)

// -------- DPP 16-lane all-reduce (sum) on the VALU pipe --------------------
template<int CTRL>
__device__ __forceinline__ float dpp_add(float x) {
    int y = __builtin_amdgcn_update_dpp(0, __float_as_int(x), CTRL, 0xF, 0xF, false);
    return x + __int_as_float(y);
}
__device__ __forceinline__ float rowred16(float p) {
    p = dpp_add<0x128>(p);  // row_ror:8
    p = dpp_add<0x124>(p);  // row_ror:4
    p = dpp_add<0x122>(p);  // row_ror:2
    p = dpp_add<0x121>(p);  // row_ror:1
    return p;               // all 16 lanes of the row hold the sum
}

// qpan slot layout (1KB per col j): row r = r16*16 + 4g + e stored at
// float idx j*256 + g*64 + ((r16 ^ 2g) << 2) + e.
__device__ __forceinline__ int qoff(int j, int g, int r16) {
    return j * 256 + g * 64 + ((r16 ^ (2 * g)) << 2);
}

// -------- transpose: in (R, S) row-major -> out (S, R) row-major ----------
__global__ __launch_bounds__(256) void tkern(const float* __restrict__ in,
                                             float* __restrict__ out,
                                             int R, int S) {
    __shared__ float tile[32][33];
    const int tx = threadIdx.x, ty = threadIdx.y;
    const int s0 = blockIdx.x * 32, r0 = blockIdx.y * 32;
    #pragma unroll
    for (int i = ty; i < 32; i += 8) {
        int r = r0 + i, s = s0 + tx;
        tile[i][tx] = (r < R && s < S) ? in[(size_t)r * S + s] : 0.f;
    }
    __syncthreads();
    #pragma unroll
    for (int i = ty; i < 32; i += 8) {
        int s = s0 + i, r = r0 + tx;
        if (s < S && r < R) out[(size_t)s * R + r] = tile[tx][i];
    }
}

// ===========================================================================
// C=64 path (register-resident MGS + chunked apply), takes thread id and an
// LDS slice so 4 sites pack into one 1024-thread block.
// ===========================================================================
template<int C, int CT, int KC>
__device__ __forceinline__ void qr_body(const float* __restrict__ W,
                                        float* __restrict__ XY,
                                        float* __restrict__ sm, int t) {
    constexpr int RT = 16;
    constexpr int TR = C / RT;
    constexpr int THREADS = RT * CT;
    constexpr int QSTR = TR + 4;
    constexpr int XSTR = C + 4;

    float* qs = sm;                       // 2 * RT*QSTR
    float* xs = sm + 2 * RT * QSTR;       // BB * XSTR
    float* qc = xs + BB * XSTR;           // KC * C

    const int rb = t & 15;
    const int cb = t >> 4;

    float a[TR][4];
    {
        const float* Wp = W + (size_t)(rb * TR) * C + cb * 4;
        #pragma unroll
        for (int i = 0; i < TR; ++i) {
            float4 v = *reinterpret_cast<const float4*>(Wp + (size_t)i * C);
            a[i][0] = v.x; a[i][1] = v.y; a[i][2] = v.z; a[i][3] = v.w;
        }
    }
    {
        #pragma unroll
        for (int v = 0; v < (BB * C) / (4 * THREADS); ++v) {
            int idx = 4 * (t + v * THREADS);
            int b = idx / C, k = idx % C;
            float4 x4 = *reinterpret_cast<const float4*>(XY + idx);
            *reinterpret_cast<float4*>(&xs[b * XSTR + k]) = x4;
        }
    }

    int buf = 0;
    #pragma unroll 1
    for (int j = 0; j < C; ++j) {
        const int cbj = j >> 2, jj = j & 3;
        if (cb == cbj) {
            #pragma unroll
            for (int q = 0; q < 4; ++q) {
                if (q == jj) {
                    float p = 0.f;
                    #pragma unroll
                    for (int i = 0; i < TR; ++i) p += a[i][q] * a[i][q];
                    p = rowred16(p);
                    const float rn = 1.0f / sqrtf(p);
                    #pragma unroll
                    for (int i = 0; i < TR; ++i) a[i][q] *= rn;
                    #pragma unroll
                    for (int i = 0; i < TR; i += 4) {
                        *reinterpret_cast<float4*>(&qs[buf * RT * QSTR + rb * QSTR + i]) =
                            make_float4(a[i][q], a[i+1][q], a[i+2][q], a[i+3][q]);
                    }
                }
            }
        }
        __syncthreads();
        if (cb * 4 + 3 > j) {
            float qv[TR];
            #pragma unroll
            for (int i = 0; i < TR; i += 4) {
                float4 v = *reinterpret_cast<const float4*>(&qs[buf * RT * QSTR + rb * QSTR + i]);
                qv[i] = v.x; qv[i+1] = v.y; qv[i+2] = v.z; qv[i+3] = v.w;
            }
            #pragma unroll
            for (int q = 0; q < 4; ++q) {
                if (cb * 4 + q > j) {
                    float p = 0.f;
                    #pragma unroll
                    for (int i = 0; i < TR; ++i) p += a[i][q] * qv[i];
                    p = rowred16(p);
                    #pragma unroll
                    for (int i = 0; i < TR; ++i) a[i][q] -= p * qv[i];
                }
            }
        }
        buf ^= 1;
    }

    const int u  = t % (C / 4);
    const int bp = t / (C / 4);
    float acc[2][4] = {{0,0,0,0},{0,0,0,0}};

    #pragma unroll 1
    for (int ch = 0; ch < C / KC; ++ch) {
        __syncthreads();
        if (cb >= (ch * KC) / 4 && cb < ((ch + 1) * KC) / 4) {
            #pragma unroll
            for (int q = 0; q < 4; ++q) {
                const int kk = cb * 4 + q - ch * KC;
                const int swz = (kk & 7) << 2;
                #pragma unroll
                for (int i = 0; i < TR; i += 4) {
                    const int cout = rb * TR + i;
                    *reinterpret_cast<float4*>(&qc[kk * C + (cout ^ swz)]) =
                        make_float4(a[i][q], a[i+1][q], a[i+2][q], a[i+3][q]);
                }
            }
        }
        __syncthreads();
        #pragma unroll
        for (int kk = 0; kk < KC; kk += 4) {
            const int k = ch * KC + kk;
            float4 x0 = *reinterpret_cast<const float4*>(&xs[(2*bp    ) * XSTR + k]);
            float4 x1 = *reinterpret_cast<const float4*>(&xs[(2*bp + 1) * XSTR + k]);
            #pragma unroll
            for (int m = 0; m < 4; ++m) {
                const int swz = ((kk + m) & 7) << 2;
                float4 qv4 = *reinterpret_cast<const float4*>(&qc[(kk + m) * C + ((4 * u) ^ swz)]);
                const float xa = (&x0.x)[m], xb = (&x1.x)[m];
                acc[0][0] += xa * qv4.x; acc[0][1] += xa * qv4.y;
                acc[0][2] += xa * qv4.z; acc[0][3] += xa * qv4.w;
                acc[1][0] += xb * qv4.x; acc[1][1] += xb * qv4.y;
                acc[1][2] += xb * qv4.z; acc[1][3] += xb * qv4.w;
            }
        }
    }
    {
        *reinterpret_cast<float4*>(XY + (2*bp    ) * C + 4 * u) =
            make_float4(acc[0][0], acc[0][1], acc[0][2], acc[0][3]);
        *reinterpret_cast<float4*>(XY + (2*bp + 1) * C + 4 * u) =
            make_float4(acc[1][0], acc[1][1], acc[1][2], acc[1][3]);
    }
}

// ===========================================================================
// C=256 left-looking 2-panel MGS (K=2 rounds, fused apply, fences).
// ===========================================================================
__device__ __forceinline__ void dot_upd(float (&a)[2][16], const float* qpan,
                                        int j, int rb) {
    const float4 q40 = *reinterpret_cast<const float4*>(&qpan[qoff(j, 0, rb)]);
    const float4 q41 = *reinterpret_cast<const float4*>(&qpan[qoff(j, 1, rb)]);
    const float4 q42 = *reinterpret_cast<const float4*>(&qpan[qoff(j, 2, rb)]);
    const float4 q43 = *reinterpret_cast<const float4*>(&qpan[qoff(j, 3, rb)]);
    float p0 = 0.f, p1 = 0.f;
    p0 += a[0][ 0]*q40.x; p1 += a[1][ 0]*q40.x;
    p0 += a[0][ 1]*q40.y; p1 += a[1][ 1]*q40.y;
    p0 += a[0][ 2]*q40.z; p1 += a[1][ 2]*q40.z;
    p0 += a[0][ 3]*q40.w; p1 += a[1][ 3]*q40.w;
    p0 += a[0][ 4]*q41.x; p1 += a[1][ 4]*q41.x;
    p0 += a[0][ 5]*q41.y; p1 += a[1][ 5]*q41.y;
    p0 += a[0][ 6]*q41.z; p1 += a[1][ 6]*q41.z;
    p0 += a[0][ 7]*q41.w; p1 += a[1][ 7]*q41.w;
    p0 += a[0][ 8]*q42.x; p1 += a[1][ 8]*q42.x;
    p0 += a[0][ 9]*q42.y; p1 += a[1][ 9]*q42.y;
    p0 += a[0][10]*q42.z; p1 += a[1][10]*q42.z;
    p0 += a[0][11]*q42.w; p1 += a[1][11]*q42.w;
    p0 += a[0][12]*q43.x; p1 += a[1][12]*q43.x;
    p0 += a[0][13]*q43.y; p1 += a[1][13]*q43.y;
    p0 += a[0][14]*q43.z; p1 += a[1][14]*q43.z;
    p0 += a[0][15]*q43.w; p1 += a[1][15]*q43.w;
    p0 = rowred16(p0); p1 = rowred16(p1);
    a[0][ 0] -= p0*q40.x; a[0][ 1] -= p0*q40.y;
    a[0][ 2] -= p0*q40.z; a[0][ 3] -= p0*q40.w;
    a[0][ 4] -= p0*q41.x; a[0][ 5] -= p0*q41.y;
    a[0][ 6] -= p0*q41.z; a[0][ 7] -= p0*q41.w;
    a[0][ 8] -= p0*q42.x; a[0][ 9] -= p0*q42.y;
    a[0][10] -= p0*q42.z; a[0][11] -= p0*q42.w;
    a[0][12] -= p0*q43.x; a[0][13] -= p0*q43.y;
    a[0][14] -= p0*q43.z; a[0][15] -= p0*q43.w;
    a[1][ 0] -= p1*q40.x; a[1][ 1] -= p1*q40.y;
    a[1][ 2] -= p1*q40.z; a[1][ 3] -= p1*q40.w;
    a[1][ 4] -= p1*q41.x; a[1][ 5] -= p1*q41.y;
    a[1][ 6] -= p1*q41.z; a[1][ 7] -= p1*q41.w;
    a[1][ 8] -= p1*q42.x; a[1][ 9] -= p1*q42.y;
    a[1][10] -= p1*q42.z; a[1][11] -= p1*q42.w;
    a[1][12] -= p1*q43.x; a[1][13] -= p1*q43.y;
    a[1][14] -= p1*q43.z; a[1][15] -= p1*q43.w;
}

__device__ __forceinline__ void mini_mgs2(float (&a)[2][16], float* qpan,
                                          int jx, int rb) {
    float p = 0.f;
    #pragma unroll
    for (int i = 0; i < 16; ++i) p += a[0][i] * a[0][i];
    p = rowred16(p);
    float rn = 1.0f / sqrtf(p);
    #pragma unroll
    for (int i = 0; i < 16; ++i) a[0][i] *= rn;
    #pragma unroll
    for (int g = 0; g < 4; ++g) {
        *reinterpret_cast<float4*>(&qpan[qoff(jx, g, rb)]) =
            make_float4(a[0][4*g], a[0][4*g+1], a[0][4*g+2], a[0][4*g+3]);
    }
    float q = 0.f;
    #pragma unroll
    for (int i = 0; i < 16; ++i) q += a[1][i] * a[0][i];
    q = rowred16(q);
    #pragma unroll
    for (int i = 0; i < 16; ++i) a[1][i] -= q * a[0][i];
    p = 0.f;
    #pragma unroll
    for (int i = 0; i < 16; ++i) p += a[1][i] * a[1][i];
    p = rowred16(p);
    rn = 1.0f / sqrtf(p);
    #pragma unroll
    for (int i = 0; i < 16; ++i) a[1][i] *= rn;
    #pragma unroll
    for (int g = 0; g < 4; ++g) {
        *reinterpret_cast<float4*>(&qpan[qoff(jx + 1, g, rb)]) =
            make_float4(a[1][4*g], a[1][4*g+1], a[1][4*g+2], a[1][4*g+3]);
    }
}

__device__ __forceinline__ void apply1(float (&y0)[4], float (&y1)[4],
                                       const float* qpan, const float* xsb,
                                       int j, int u, int v) {
    float4 q4 = *reinterpret_cast<const float4*>(&qpan[qoff(j, u & 3, u >> 2)]);
    const float xa = xsb[j*33 + 2*v];
    const float xb = xsb[j*33 + 2*v + 1];
    y0[0] += xa*q4.x; y0[1] += xa*q4.y; y0[2] += xa*q4.z; y0[3] += xa*q4.w;
    y1[0] += xb*q4.x; y1[1] += xb*q4.y; y1[2] += xb*q4.z; y1[3] += xb*q4.w;
}

__device__ void panel_mgs(float (&a)[2][16], float (&y0)[4], float (&y1)[4],
                          float* qpan, const float* xsb,
                          int rb, int cb, int u, int v) {
    if (cb == 0) mini_mgs2(a, qpan, 0, rb);
    __syncthreads();   // also orders xsb staging / qpan prologue writes
    #pragma unroll 1
    for (int m = 0; m < 64; ++m) {
        apply1(y0, y1, qpan, xsb, 2*m,     u, v);
        apply1(y0, y1, qpan, xsb, 2*m + 1, u, v);
        SCHED_FENCE();
        if (cb > m) {
            dot_upd(a, qpan, 2*m,     rb);
            SCHED_FENCE();
            dot_upd(a, qpan, 2*m + 1, rb);
            SCHED_FENCE();
            if (cb == m + 1) mini_mgs2(a, qpan, 2*m + 2, rb);
        }
        __syncthreads();
    }
}

__device__ __forceinline__ void qr256_site(const float* __restrict__ Wp,
                                           float* __restrict__ Xp,
                                           float* __restrict__ sm, int t) {
    float* qpan = sm;            // 128 KiB: finished q's, 1KB/col slot
    float* xsb  = sm + 32768;    // 16.5 KiB: X panel [col][b], pad 33

    const int rb = t & 15;
    const int cb = t >> 4;
    const int u  = t & 63;
    const int v  = t >> 6;

    float a[2][16];
    float y0[4] = {0,0,0,0};
    float y1[4] = {0,0,0,0};

    // ---- panel 0: load W cols [0,128) + stage X cols [0,128) ----
    #pragma unroll
    for (int i = 0; i < 16; ++i) {
        float2 w2 = *reinterpret_cast<const float2*>(
            Wp + (size_t)(rb*16 + i) * 256 + 2*cb);
        a[0][i] = w2.x; a[1][i] = w2.y;
    }
    {
        const int tj = t & 127, tb = t >> 7;
        #pragma unroll
        for (int d = 0; d < 4; ++d)
            xsb[tj*33 + 4*tb + d] = Xp[(4*tb + d)*256 + tj];
    }
    panel_mgs(a, y0, y1, qpan, xsb, rb, cb, u, v);

    // ---- glue: reload W cols [128,256), restage X, cross-pass ----
    __syncthreads();   // panel-0 consumers done before xsb is overwritten
    #pragma unroll
    for (int i = 0; i < 16; ++i) {
        float2 w2 = *reinterpret_cast<const float2*>(
            Wp + (size_t)(rb*16 + i) * 256 + 128 + 2*cb);
        a[0][i] = w2.x; a[1][i] = w2.y;
    }
    {
        const int tj = t & 127, tb = t >> 7;
        #pragma unroll
        for (int d = 0; d < 4; ++d)
            xsb[tj*33 + 4*tb + d] = Xp[(4*tb + d)*256 + 128 + tj];
    }
    // cross-pass: orthogonalize both register cols vs Q0 (barrier-free;
    // qpan read-only here, xsb writes touch a disjoint region)
    #pragma unroll 1
    for (int k = 0; k < 128; ++k) {
        dot_upd(a, qpan, k, rb);
        SCHED_FENCE();
    }
    __syncthreads();

    // ---- panel 1 ----
    panel_mgs(a, y0, y1, qpan, xsb, rb, cb, u, v);

    // ---- write Y in place over X (coalesced float4) ----
    *reinterpret_cast<float4*>(Xp + (size_t)(2*v    )*256 + 4*u) =
        make_float4(y0[0], y0[1], y0[2], y0[3]);
    *reinterpret_cast<float4*>(Xp + (size_t)(2*v + 1)*256 + 4*u) =
        make_float4(y1[0], y1[1], y1[2], y1[3]);
}

// ===========================================================================
// Mega-kernel: 256 blocks x 1024 thr, LDS 148KB -> 1 block/CU.
//   blocks 0..195: one C=256 site.  blocks 196..255: packed 4x C=64 sites.
// ===========================================================================
static constexpr int SM64 = 2*16*8 + 32*68 + 64*64;   // 6528 floats per site

__global__ __launch_bounds__(1024) void qr_all(const float* __restrict__ W0,
                                               const float* __restrict__ W1,
                                               float* __restrict__ XY0,
                                               float* __restrict__ XY1) {
    __shared__ float sm[32768 + 128*33];   // 36992 floats = 147,968 B
    const int bid = blockIdx.x;
    const int t   = threadIdx.x;
    if (bid < 196) {
        qr256_site(W1 + (size_t)bid * 65536, XY1 + (size_t)bid * 8192, sm, t);
    } else {
        const int sl = t >> 8;     // sub-site 0..3
        const int tt = t & 255;
        float* smL = sm + sl * SM64;
        #pragma unroll 1
        for (int uu = bid - 196; uu < 196; uu += 60) {
            const int site = 4 * uu + sl;
            qr_body<64, 16, 64>(W0 + (size_t)site * 4096,
                                XY0 + (size_t)site * 2048, smL, tt);
            __syncthreads();   // LDS slice safe to reuse next unit
        }
    }
}

extern "C" void kernel_launch(void* const* d_in, const int* in_sizes, int n_in,
                              void* d_out, int out_size, void* d_ws, size_t ws_size,
                              hipStream_t stream) {
    (void)in_sizes; (void)n_in; (void)out_size; (void)ws_size;
    const float* x0 = (const float*)d_in[0];  // (32, 64, 784)
    const float* x1 = (const float*)d_in[1];  // (32, 256, 196)
    const float* W0 = (const float*)d_in[2];  // (784, 64, 64)
    const float* W1 = (const float*)d_in[3];  // (196, 256, 256)
    float* y0  = (float*)d_out;               // (32, 64, 784) flat
    float* y1  = y0 + 1605632;                // (32, 256, 196) flat
    float* xt0 = (float*)d_ws;                // (784, 32*64)
    float* xt1 = xt0 + 1605632;               // (196, 32*256)

    dim3 tb(32, 8);
    // x (B*C, S) -> xt (S, B*C)
    tkern<<<dim3(25,  64), tb, 0, stream>>>(x0, xt0, 2048, 784);
    tkern<<<dim3(7,  256), tb, 0, stream>>>(x1, xt1, 8192, 196);
    // fused QR + apply, both problems in one dispatch (Y overwrites xt)
    qr_all<<<256, 1024, 0, stream>>>(W0, W1, xt0, xt1);
    // xt (S, B*C) -> y (B*C, S)
    tkern<<<dim3(64,  25), tb, 0, stream>>>(xt0, y0, 784, 2048);
    tkern<<<dim3(256,  7), tb, 0, stream>>>(xt1, y1, 196, 8192);
}